// Round 5
// baseline (221.961 us; speedup 1.0000x reference)
//
#include <hip/hip_runtime.h>
#include <hip/hip_bf16.h>
#include <stdint.h>

typedef __attribute__((ext_vector_type(8))) short short8;
typedef __attribute__((ext_vector_type(4))) float floatx4;

using bf16 = __hip_bfloat16;

// QK_SCALE * LOG2E folded: scores arrive pre-scaled to log2 domain
#define SCALE_L2 0.12751793359133147f

__device__ inline unsigned short f2b(float f) {
    bf16 h = __float2bfloat16(f);
    return *(unsigned short*)&h;
}

// ---------------------------------------------------------------------------
// Fused prep: enc f32->bf16 (blocks 0..8191) + weight transposes (blocks 8192+)
// ---------------------------------------------------------------------------
__global__ __launch_bounds__(256) void prep_all(const float4* __restrict__ enc4,
                                                ushort4* __restrict__ encb4,
                                                const float* __restrict__ Wq,
                                                const float* __restrict__ Wk,
                                                const float* __restrict__ Wv,
                                                const float* __restrict__ Wo,
                                                bf16* __restrict__ Wqkvt,
                                                bf16* __restrict__ Wot) {
    int bx = blockIdx.x;
    if (bx < 8192) {
        int i = bx * 256 + threadIdx.x;  // 2,097,152 float4
        float4 v = enc4[i];
        ushort4 o;
        o.x = f2b(v.x); o.y = f2b(v.y); o.z = f2b(v.z); o.w = f2b(v.w);
        encb4[i] = o;
    } else {
        int idx = (bx - 8192) * 256 + threadIdx.x;  // 4 * 131072
        int sel = idx >> 17;
        int i = idx & 131071;
        if (sel < 3) {
            const float* W = (sel == 0) ? Wq : (sel == 1) ? Wk : Wv;
            int r = i >> 7, c = i & 127;  // src [1024][128]
            Wqkvt[(size_t)(sel * 128 + c) * 1024 + r] = __float2bfloat16(W[i]);
        } else {
            int r = i >> 10, c = i & 1023;  // src [128][1024]
            Wot[(size_t)c * 128 + r] = __float2bfloat16(Wo[i]);
        }
    }
}

// ---------------------------------------------------------------------------
// QKV GEMM, 64x64 tiles: grid (128, 6). C tile = encb[64,1024] * Wqkvt[64,1024]^T
// 4 waves as 2x2 (wave = 32x32, acc[2][2]). Register prefetch, 3 blocks/CU.
// ---------------------------------------------------------------------------
__global__ __launch_bounds__(256) void gemm_qkv64(const bf16* __restrict__ A,
                                                  const bf16* __restrict__ Bt,
                                                  bf16* __restrict__ Qb,
                                                  bf16* __restrict__ Kb,
                                                  bf16* __restrict__ Vtb) {
    __shared__ bf16 As[64 * 40];
    __shared__ bf16 Bs[64 * 40];

    const int tid = threadIdx.x;
    const int m0 = blockIdx.x * 64;
    const int brow0 = blockIdx.y * 64;          // within [0,384)
    const int proj = brow0 >> 7;                // 0=Q 1=K 2=V (uniform per block)
    const int colb = brow0 & 127;               // col base within projection
    const int w = tid >> 6, lane = tid & 63;
    const int wm = (w >> 1) * 32, wn = (w & 1) * 32;
    const int quad = lane >> 4, l16 = lane & 15;

    const int ra = tid >> 2, ca = (tid & 3) * 8;  // 1 int4/thread each tile

    floatx4 acc[2][2];
#pragma unroll
    for (int i = 0; i < 2; i++)
#pragma unroll
        for (int j = 0; j < 2; j++) acc[i][j] = (floatx4){0.f, 0.f, 0.f, 0.f};

    int4 pa = *(const int4*)&A[(size_t)(m0 + ra) * 1024 + ca];
    int4 pb = *(const int4*)&Bt[(size_t)(brow0 + ra) * 1024 + ca];

    for (int k0 = 0; k0 < 1024; k0 += 32) {
        __syncthreads();
        *(int4*)&As[ra * 40 + ca] = pa;
        *(int4*)&Bs[ra * 40 + ca] = pb;
        __syncthreads();

        if (k0 + 32 < 1024) {
            pa = *(const int4*)&A[(size_t)(m0 + ra) * 1024 + k0 + 32 + ca];
            pb = *(const int4*)&Bt[(size_t)(brow0 + ra) * 1024 + k0 + 32 + ca];
        }

        short8 a[2], b[2];
#pragma unroll
        for (int mt = 0; mt < 2; mt++)
            a[mt] = *(const short8*)&As[(wm + mt * 16 + l16) * 40 + quad * 8];
#pragma unroll
        for (int nt = 0; nt < 2; nt++)
            b[nt] = *(const short8*)&Bs[(wn + nt * 16 + l16) * 40 + quad * 8];
#pragma unroll
        for (int mt = 0; mt < 2; mt++)
#pragma unroll
            for (int nt = 0; nt < 2; nt++)
                acc[mt][nt] = __builtin_amdgcn_mfma_f32_16x16x32_bf16(a[mt], b[nt], acc[mt][nt], 0, 0, 0);
    }

#pragma unroll
    for (int mt = 0; mt < 2; mt++)
#pragma unroll
        for (int nt = 0; nt < 2; nt++)
#pragma unroll
            for (int r = 0; r < 4; r++) {
                int row = m0 + wm + mt * 16 + quad * 4 + r;
                int col = colb + wn + nt * 16 + l16;  // 0..127 within projection
                bf16 h = __float2bfloat16(acc[mt][nt][r]);
                if (proj == 0) {
                    Qb[(size_t)row * 128 + col] = h;
                } else if (proj == 1) {
                    Kb[(size_t)row * 128 + col] = h;
                } else {
                    int bb = row >> 11, ss = row & 2047;
                    Vtb[(size_t)bb * 262144 + (size_t)col * 2048 + ss] = h;
                }
            }
}

// ---------------------------------------------------------------------------
// Out-proj GEMM: C[8192,1024] = Sc[8192,128] * Wot[1024,128]^T, f32 out.
// 64x128 tiles, grid (128, 8). Register prefetch.
// ---------------------------------------------------------------------------
__global__ __launch_bounds__(256) void gemm_out(const bf16* __restrict__ A,
                                                const bf16* __restrict__ Bt,
                                                float* __restrict__ C) {
    __shared__ bf16 As[64 * 40];
    __shared__ bf16 Bs[128 * 40];

    const int tid = threadIdx.x;
    const int m0 = blockIdx.x * 64;
    const int n0 = blockIdx.y * 128;
    const int w = tid >> 6, lane = tid & 63;
    const int wm = (w >> 1) * 32, wn = (w & 1) * 64;
    const int quad = lane >> 4, l16 = lane & 15;

    const int ra = tid >> 2, ca = (tid & 3) * 8;
    const int rb0 = tid >> 2, rb1 = (tid + 256) >> 2;

    floatx4 acc[2][4];
#pragma unroll
    for (int i = 0; i < 2; i++)
#pragma unroll
        for (int j = 0; j < 4; j++) acc[i][j] = (floatx4){0.f, 0.f, 0.f, 0.f};

    int4 pa  = *(const int4*)&A[(size_t)(m0 + ra) * 128 + ca];
    int4 pb0 = *(const int4*)&Bt[(size_t)(n0 + rb0) * 128 + ca];
    int4 pb1 = *(const int4*)&Bt[(size_t)(n0 + rb1) * 128 + ca];

    for (int k0 = 0; k0 < 128; k0 += 32) {
        __syncthreads();
        *(int4*)&As[ra * 40 + ca] = pa;
        *(int4*)&Bs[rb0 * 40 + ca] = pb0;
        *(int4*)&Bs[rb1 * 40 + ca] = pb1;
        __syncthreads();

        if (k0 + 32 < 128) {
            pa  = *(const int4*)&A[(size_t)(m0 + ra) * 128 + k0 + 32 + ca];
            pb0 = *(const int4*)&Bt[(size_t)(n0 + rb0) * 128 + k0 + 32 + ca];
            pb1 = *(const int4*)&Bt[(size_t)(n0 + rb1) * 128 + k0 + 32 + ca];
        }

        short8 a[2], b[4];
#pragma unroll
        for (int mt = 0; mt < 2; mt++)
            a[mt] = *(const short8*)&As[(wm + mt * 16 + l16) * 40 + quad * 8];
#pragma unroll
        for (int nt = 0; nt < 4; nt++)
            b[nt] = *(const short8*)&Bs[(wn + nt * 16 + l16) * 40 + quad * 8];
#pragma unroll
        for (int mt = 0; mt < 2; mt++)
#pragma unroll
            for (int nt = 0; nt < 4; nt++)
                acc[mt][nt] = __builtin_amdgcn_mfma_f32_16x16x32_bf16(a[mt], b[nt], acc[mt][nt], 0, 0, 0);
    }

#pragma unroll
    for (int mt = 0; mt < 2; mt++)
#pragma unroll
        for (int nt = 0; nt < 4; nt++)
#pragma unroll
            for (int r = 0; r < 4; r++) {
                int row = m0 + wm + mt * 16 + quad * 4 + r;
                int col = n0 + wn + nt * 16 + l16;
                C[(size_t)row * 1024 + col] = acc[mt][nt][r];
            }
}

// ---------------------------------------------------------------------------
// Flash attention v3: BARRIER-FREE k-loop. S^T = K*Q^T, O^T = V^T*P^T.
// K/V operand frags read DIRECTLY from global (L2-hot, 2MB/batch, XCD-local
// since all 4 ks-splits of one (b,qt) map to the same XCD). Only the per-wave
// P strip uses LDS (same-wave RAW, no barrier). grid (128, 4).
// LDS 9216 B; waves fully async -> latency hidden by occupancy.
// ---------------------------------------------------------------------------
__global__ __launch_bounds__(256) void flash_split(const bf16* __restrict__ Q,
                                                   const bf16* __restrict__ K,
                                                   const bf16* __restrict__ Vt,
                                                   float* __restrict__ Op,
                                                   float2* __restrict__ Ml) {
    __shared__ bf16 Ps[4 * 16 * 72];  // per-wave strip: [w][qrow16][64+8]

    const int tid = threadIdx.x;
    const int b = blockIdx.x >> 5;
    const int qt = blockIdx.x & 31;
    const int ks = blockIdx.y;
    const int q0 = qt * 64;
    const int w = tid >> 6, lane = tid & 63;
    const int quad = lane >> 4, l16 = lane & 15;

    const int ntiles = qt + 1;
    const int per = (ntiles + 3) >> 2;
    const int start = ks * per;
    const int end = min(start + per, ntiles);

    // Q B-frag from global: lane l16 -> qrow, k = quad*8+j
    const int qrow = q0 + w * 16 + l16;
    const bf16* Qrow = &Q[((size_t)b * 2048 + qrow) * 128];
    short8 qf[4];
#pragma unroll
    for (int k4 = 0; k4 < 4; k4++)
        qf[k4] = *(const short8*)&Qrow[k4 * 32 + quad * 8];

    const bf16* Kb = &K[(size_t)b * 2048 * 128];
    const bf16* Vb = &Vt[(size_t)b * 262144];

    float m_run = -1.0e30f, l_run = 0.f;  // per-lane q-row stats (log2 domain)
    floatx4 o[8];                         // O^T: col qrow=l16, rows d
#pragma unroll
    for (int d = 0; d < 8; d++) o[d] = (floatx4){0.f, 0.f, 0.f, 0.f};

    for (int kt = start; kt < end; kt++) {
        const bf16* Kt = Kb + (size_t)(kt * 64) * 128;
        const bf16* Vtt = Vb + kt * 64;

        // S^T = K * Q^T : A-frags = K rows (kcols) straight from global.
        // quad-pairs make each 16-row frag read 16 full 64B lines (coalesced).
        floatx4 s_acc[4];
#pragma unroll
        for (int nt = 0; nt < 4; nt++) {
            s_acc[nt] = (floatx4){0.f, 0.f, 0.f, 0.f};
#pragma unroll
            for (int k4 = 0; k4 < 4; k4++) {
                short8 kf = *(const short8*)&Kt[(size_t)(nt * 16 + l16) * 128 + k4 * 32 + quad * 8];
                s_acc[nt] = __builtin_amdgcn_mfma_f32_16x16x32_bf16(kf, qf[k4], s_acc[nt], 0, 0, 0);
            }
        }

        // per-lane 16 scores for q-row qrow, kcols kt*64 + nt*16 + quad*4 + r
        float sv[4][4];
#pragma unroll
        for (int nt = 0; nt < 4; nt++)
#pragma unroll
            for (int r = 0; r < 4; r++) {
                float s = s_acc[nt][r] * SCALE_L2;  // log2 domain
                if (kt == qt) {
                    int kcol = kt * 64 + nt * 16 + quad * 4 + r;
                    if (kcol > qrow) s = -1.0e9f;
                }
                sv[nt][r] = s;
            }

        float t0 = fmaxf(fmaxf(sv[0][0], sv[0][1]), fmaxf(sv[0][2], sv[0][3]));
        float t1 = fmaxf(fmaxf(sv[1][0], sv[1][1]), fmaxf(sv[1][2], sv[1][3]));
        float t2 = fmaxf(fmaxf(sv[2][0], sv[2][1]), fmaxf(sv[2][2], sv[2][3]));
        float t3 = fmaxf(fmaxf(sv[3][0], sv[3][1]), fmaxf(sv[3][2], sv[3][3]));
        float tmax = fmaxf(fmaxf(t0, t1), fmaxf(t2, t3));
        tmax = fmaxf(tmax, __shfl_xor(tmax, 16));
        tmax = fmaxf(tmax, __shfl_xor(tmax, 32));

        float mnew = fmaxf(m_run, tmax);
        float alpha = exp2f(m_run - mnew);
        m_run = mnew;

        float rsum = 0.f;
#pragma unroll
        for (int nt = 0; nt < 4; nt++)
#pragma unroll
            for (int r = 0; r < 4; r++) {
                float p = exp2f(sv[nt][r] - mnew);
                sv[nt][r] = p;
                rsum += p;
            }
        rsum += __shfl_xor(rsum, 16);
        rsum += __shfl_xor(rsum, 32);
        l_run = l_run * alpha + rsum;

        // P strip (per-wave, no barrier): Ps[w][l16=qrow][kcol 0..63]
#pragma unroll
        for (int nt = 0; nt < 4; nt++) {
            ushort4 pk;
            pk.x = f2b(sv[nt][0]); pk.y = f2b(sv[nt][1]);
            pk.z = f2b(sv[nt][2]); pk.w = f2b(sv[nt][3]);
            *(ushort4*)&Ps[w * 1152 + l16 * 72 + nt * 16 + quad * 4] = pk;
        }

#pragma unroll
        for (int d = 0; d < 8; d++) {
            o[d][0] *= alpha; o[d][1] *= alpha; o[d][2] *= alpha; o[d][3] *= alpha;
        }

        // O^T += V^T * P^T : A-frags = Vt rows from global, B = P strip
        short8 pf[2];
#pragma unroll
        for (int k2 = 0; k2 < 2; k2++)
            pf[k2] = *(const short8*)&Ps[w * 1152 + l16 * 72 + k2 * 32 + quad * 8];
#pragma unroll
        for (int d = 0; d < 8; d++)
#pragma unroll
            for (int k2 = 0; k2 < 2; k2++) {
                short8 vf = *(const short8*)&Vtt[(size_t)(d * 16 + l16) * 2048 + k2 * 32 + quad * 8];
                o[d] = __builtin_amdgcn_mfma_f32_16x16x32_bf16(vf, pf[k2], o[d], 0, 0, 0);
            }
    }

    // epilogue: unnormalized O^T partials -> Op[ks][qrow][d], float4 stores
    const size_t orow = (size_t)ks * 8192 + b * 2048 + qrow;
#pragma unroll
    for (int d = 0; d < 8; d++) {
        float4 v = {o[d][0], o[d][1], o[d][2], o[d][3]};
        *(float4*)&Op[orow * 128 + d * 16 + quad * 4] = v;
    }
    if (lane < 16) Ml[orow] = make_float2(m_run, l_run);
}

// ---------------------------------------------------------------------------
// Merge 4 K-split partials -> normalized bf16 scores Sc[8192][128]
// (m values are in log2 domain)
// ---------------------------------------------------------------------------
__global__ __launch_bounds__(256) void flash_merge(const float* __restrict__ Op,
                                                   const float2* __restrict__ Ml,
                                                   bf16* __restrict__ Sc) {
    int idx = blockIdx.x * 256 + threadIdx.x;  // 8192*32
    int row = idx >> 5, dg = (idx & 31) * 4;

    float2 ml[4];
#pragma unroll
    for (int s = 0; s < 4; s++) ml[s] = Ml[(size_t)s * 8192 + row];
    float M = fmaxf(fmaxf(ml[0].x, ml[1].x), fmaxf(ml[2].x, ml[3].x));
    float L = 0.f, wgt[4];
#pragma unroll
    for (int s = 0; s < 4; s++) {
        wgt[s] = exp2f(ml[s].x - M);
        L += ml[s].y * wgt[s];
    }
    float4 acc = {0.f, 0.f, 0.f, 0.f};
#pragma unroll
    for (int s = 0; s < 4; s++) {
        float4 v = *(const float4*)&Op[((size_t)s * 8192 + row) * 128 + dg];
        acc.x += v.x * wgt[s]; acc.y += v.y * wgt[s];
        acc.z += v.z * wgt[s]; acc.w += v.w * wgt[s];
    }
    float inv = 1.0f / L;
    ushort4 o;
    o.x = f2b(acc.x * inv); o.y = f2b(acc.y * inv);
    o.z = f2b(acc.z * inv); o.w = f2b(acc.w * inv);
    *(ushort4*)&Sc[(size_t)row * 128 + dg] = o;
}

// ---------------------------------------------------------------------------
extern "C" void kernel_launch(void* const* d_in, const int* in_sizes, int n_in,
                              void* d_out, int out_size, void* d_ws, size_t ws_size,
                              hipStream_t stream) {
    const float* enc = (const float*)d_in[0];
    // d_in[1] = mask: known causal triu(k=1); implemented analytically.
    const float* Wq = (const float*)d_in[2];
    const float* Wk = (const float*)d_in[3];
    const float* Wv = (const float*)d_in[4];
    const float* Wo = (const float*)d_in[5];
    float* out = (float*)d_out;

    const size_t MB = 1024 * 1024;
    char* ws = (char*)d_ws;
    bf16*   encb  = (bf16*)(ws);                    // 16 MB (dead after gemm_qkv)
    float*  Op    = (float*)(ws);                   // 16 MB, aliases encb
    bf16*   Qb    = (bf16*)(ws + 16 * MB);          // 2 MB
    bf16*   Kb    = (bf16*)(ws + 18 * MB);          // 2 MB
    bf16*   Vtb   = (bf16*)(ws + 20 * MB);          // 2 MB  [B][128][2048]
    bf16*   Scb   = (bf16*)(ws + 22 * MB);          // 2 MB
    bf16*   Wqkvt = (bf16*)(ws + 24 * MB);          // 768 KB [384][1024]
    bf16*   Wot   = (bf16*)(ws + 24 * MB + 768 * 1024);   // 256 KB [1024][128]
    float2* Ml    = (float2*)(ws + 25 * MB);        // 256 KB [4][8192]

    prep_all<<<10240, 256, 0, stream>>>((const float4*)enc, (ushort4*)encb,
                                        Wq, Wk, Wv, Wo, Wqkvt, Wot);

    dim3 blk(256);
    gemm_qkv64<<<dim3(128, 6), blk, 0, stream>>>(encb, Wqkvt, Qb, Kb, Vtb);

    flash_split<<<dim3(128, 4), blk, 0, stream>>>(Qb, Kb, Vtb, Op, Ml);
    flash_merge<<<1024, blk, 0, stream>>>(Op, Ml, Scb);

    gemm_out<<<dim3(128, 8), blk, 0, stream>>>(Scb, Wot, out);
}

// Round 6
// 210.950 us; speedup vs baseline: 1.0522x; 1.0522x over previous
//
#include <hip/hip_runtime.h>
#include <hip/hip_bf16.h>
#include <stdint.h>

typedef __attribute__((ext_vector_type(8))) short short8;
typedef __attribute__((ext_vector_type(4))) float floatx4;

using bf16 = __hip_bfloat16;

// QK_SCALE * LOG2E folded: scores arrive pre-scaled to log2 domain
#define SCALE_L2 0.12751793359133147f

__device__ inline unsigned short f2b(float f) {
    bf16 h = __float2bfloat16(f);
    return *(unsigned short*)&h;
}
__device__ inline float b2f(unsigned short u) {
    union { unsigned int i; float f; } v;
    v.i = ((unsigned int)u) << 16;
    return v.f;
}

// async global->LDS, 16B/lane; LDS dest = wave-uniform base + lane*16
__device__ __forceinline__ void gll16(const bf16* g, bf16* l) {
    __builtin_amdgcn_global_load_lds((__attribute__((address_space(1))) void*)g,
                                     (__attribute__((address_space(3))) void*)l,
                                     16, 0, 0);
}

// ---------------------------------------------------------------------------
// Fused prep: enc f32->bf16 (blocks 0..8191) + weight transposes (blocks 8192+)
// ---------------------------------------------------------------------------
__global__ __launch_bounds__(256) void prep_all(const float4* __restrict__ enc4,
                                                ushort4* __restrict__ encb4,
                                                const float* __restrict__ Wq,
                                                const float* __restrict__ Wk,
                                                const float* __restrict__ Wv,
                                                const float* __restrict__ Wo,
                                                bf16* __restrict__ Wqkvt,
                                                bf16* __restrict__ Wot) {
    int bx = blockIdx.x;
    if (bx < 8192) {
        int i = bx * 256 + threadIdx.x;  // 2,097,152 float4
        float4 v = enc4[i];
        ushort4 o;
        o.x = f2b(v.x); o.y = f2b(v.y); o.z = f2b(v.z); o.w = f2b(v.w);
        encb4[i] = o;
    } else {
        int idx = (bx - 8192) * 256 + threadIdx.x;  // 4 * 131072
        int sel = idx >> 17;
        int i = idx & 131071;
        if (sel < 3) {
            const float* W = (sel == 0) ? Wq : (sel == 1) ? Wk : Wv;
            int r = i >> 7, c = i & 127;  // src [1024][128]
            Wqkvt[(size_t)(sel * 128 + c) * 1024 + r] = __float2bfloat16(W[i]);
        } else {
            int r = i >> 10, c = i & 1023;  // src [128][1024]
            Wot[(size_t)c * 128 + r] = __float2bfloat16(Wo[i]);
        }
    }
}

// ---------------------------------------------------------------------------
// QKV GEMM, m97-style: 64x128 tiles, BK=32, grid (128,3).
// Staging via global_load_lds width-16 into unpadded lane-ordered LDS [r][32].
// 4 waves 2x2 (wave = 32x64, acc[2][4], 8 MFMA/k-iter).
// ---------------------------------------------------------------------------
__global__ __launch_bounds__(256) void gemm_qkv(const bf16* __restrict__ A,
                                                const bf16* __restrict__ Bt,
                                                bf16* __restrict__ Qb,
                                                bf16* __restrict__ Kb,
                                                bf16* __restrict__ Vtb) {
    __shared__ bf16 As[64 * 32];    // unpadded: gll lane-order = [r][32]
    __shared__ bf16 Bs[128 * 32];

    const int tid = threadIdx.x;
    const int m0 = blockIdx.x * 64;
    const int nsel = blockIdx.y;          // 0=Q 1=K 2=V
    const int brow0 = nsel * 128;
    const int w = tid >> 6, lane = tid & 63;
    const int wm = (w >> 1) * 32, wn = (w & 1) * 64;
    const int quad = lane >> 4, l16 = lane & 15;

    // staging: lane t covers LDS elems [t*8, t*8+8) => row t>>2, kcol (t&3)*8
    const int ar = tid >> 2, akq = (tid & 3) * 8;
    const int br1 = (tid + 256) >> 2;
    bf16* As_w  = &As[w * 512];           // wave-uniform LDS bases
    bf16* Bs_w0 = &Bs[w * 512];
    bf16* Bs_w1 = &Bs[2048 + w * 512];

    floatx4 acc[2][4];
#pragma unroll
    for (int i = 0; i < 2; i++)
#pragma unroll
        for (int j = 0; j < 4; j++) acc[i][j] = (floatx4){0.f, 0.f, 0.f, 0.f};

    for (int k0 = 0; k0 < 1024; k0 += 32) {
        __syncthreads();  // protect LDS reuse
        gll16(&A[(size_t)(m0 + ar) * 1024 + k0 + akq], As_w);
        gll16(&Bt[(size_t)(brow0 + ar) * 1024 + k0 + akq], Bs_w0);
        gll16(&Bt[(size_t)(brow0 + br1) * 1024 + k0 + akq], Bs_w1);
        __syncthreads();  // vmcnt(0) drain -> LDS filled

        short8 a[2], b[4];
#pragma unroll
        for (int mt = 0; mt < 2; mt++)
            a[mt] = *(const short8*)&As[(wm + mt * 16 + l16) * 32 + quad * 8];
#pragma unroll
        for (int nt = 0; nt < 4; nt++)
            b[nt] = *(const short8*)&Bs[(wn + nt * 16 + l16) * 32 + quad * 8];
#pragma unroll
        for (int mt = 0; mt < 2; mt++)
#pragma unroll
            for (int nt = 0; nt < 4; nt++)
                acc[mt][nt] = __builtin_amdgcn_mfma_f32_16x16x32_bf16(a[mt], b[nt], acc[mt][nt], 0, 0, 0);
    }

#pragma unroll
    for (int mt = 0; mt < 2; mt++)
#pragma unroll
        for (int nt = 0; nt < 4; nt++)
#pragma unroll
            for (int r = 0; r < 4; r++) {
                int row = m0 + wm + mt * 16 + quad * 4 + r;
                int col = wn + nt * 16 + l16;  // 0..127 within projection
                bf16 h = __float2bfloat16(acc[mt][nt][r]);
                if (nsel == 0) {
                    Qb[(size_t)row * 128 + col] = h;
                } else if (nsel == 1) {
                    Kb[(size_t)row * 128 + col] = h;
                } else {
                    int bb = row >> 11, ss = row & 2047;
                    Vtb[(size_t)bb * 262144 + (size_t)col * 2048 + ss] = h;
                }
            }
}

// ---------------------------------------------------------------------------
// Out-proj GEMM: C[8192,1024] = Sc[8192,128] * Wot[1024,128]^T, f32 out.
// 64x128 tiles, grid (128, 8). Register prefetch.
// ---------------------------------------------------------------------------
__global__ __launch_bounds__(256) void gemm_out(const bf16* __restrict__ A,
                                                const bf16* __restrict__ Bt,
                                                float* __restrict__ C) {
    __shared__ bf16 As[64 * 40];
    __shared__ bf16 Bs[128 * 40];

    const int tid = threadIdx.x;
    const int m0 = blockIdx.x * 64;
    const int n0 = blockIdx.y * 128;
    const int w = tid >> 6, lane = tid & 63;
    const int wm = (w >> 1) * 32, wn = (w & 1) * 64;
    const int quad = lane >> 4, l16 = lane & 15;

    const int ra = tid >> 2, ca = (tid & 3) * 8;
    const int rb0 = tid >> 2, rb1 = (tid + 256) >> 2;

    floatx4 acc[2][4];
#pragma unroll
    for (int i = 0; i < 2; i++)
#pragma unroll
        for (int j = 0; j < 4; j++) acc[i][j] = (floatx4){0.f, 0.f, 0.f, 0.f};

    int4 pa  = *(const int4*)&A[(size_t)(m0 + ra) * 128 + ca];
    int4 pb0 = *(const int4*)&Bt[(size_t)(n0 + rb0) * 128 + ca];
    int4 pb1 = *(const int4*)&Bt[(size_t)(n0 + rb1) * 128 + ca];

    for (int k0 = 0; k0 < 128; k0 += 32) {
        __syncthreads();
        *(int4*)&As[ra * 40 + ca] = pa;
        *(int4*)&Bs[rb0 * 40 + ca] = pb0;
        *(int4*)&Bs[rb1 * 40 + ca] = pb1;
        __syncthreads();

        if (k0 + 32 < 128) {
            pa  = *(const int4*)&A[(size_t)(m0 + ra) * 128 + k0 + 32 + ca];
            pb0 = *(const int4*)&Bt[(size_t)(n0 + rb0) * 128 + k0 + 32 + ca];
            pb1 = *(const int4*)&Bt[(size_t)(n0 + rb1) * 128 + k0 + 32 + ca];
        }

        short8 a[2], b[4];
#pragma unroll
        for (int mt = 0; mt < 2; mt++)
            a[mt] = *(const short8*)&As[(wm + mt * 16 + l16) * 40 + quad * 8];
#pragma unroll
        for (int nt = 0; nt < 4; nt++)
            b[nt] = *(const short8*)&Bs[(wn + nt * 16 + l16) * 40 + quad * 8];
#pragma unroll
        for (int mt = 0; mt < 2; mt++)
#pragma unroll
            for (int nt = 0; nt < 4; nt++)
                acc[mt][nt] = __builtin_amdgcn_mfma_f32_16x16x32_bf16(a[mt], b[nt], acc[mt][nt], 0, 0, 0);
    }

#pragma unroll
    for (int mt = 0; mt < 2; mt++)
#pragma unroll
        for (int nt = 0; nt < 4; nt++)
#pragma unroll
            for (int r = 0; r < 4; r++) {
                int row = m0 + wm + mt * 16 + quad * 4 + r;
                int col = n0 + wn + nt * 16 + l16;
                C[(size_t)row * 1024 + col] = acc[mt][nt][r];
            }
}

// ---------------------------------------------------------------------------
// Flash attention v4: BALANCED chunks. Per batch, qt's causal range is cut
// into ceil((qt+1)/4) chunks of <=4 k-tiles -> 144 chunks/batch, grid 576,
// every block does <=4 tiles (uniform) and all are co-resident (3 blk/CU).
// Body = R4-proven: LDS-staged K/V + register prefetch, per-lane row stats
// (S^T = K*Q^T), per-wave P strip. Partials stored bf16.
// ---------------------------------------------------------------------------
__global__ __launch_bounds__(256) void flash_split(const bf16* __restrict__ Q,
                                                   const bf16* __restrict__ K,
                                                   const bf16* __restrict__ Vt,
                                                   bf16* __restrict__ Opb,
                                                   float2* __restrict__ Ml) {
    __shared__ bf16 Ks[64 * 136];
    __shared__ bf16 Vs[128 * 72];
    __shared__ bf16 Ps[4 * 16 * 72];

    const int tid = threadIdx.x;
    const int x = blockIdx.x;          // global chunk id, [0, 576)
    const int b = x / 144;
    const int id = x - b * 144;
    // group g = qt>>2; group g starts at chunk offset 2g(g+1), has 4(g+1) chunks
    const int g = (id >= 112) ? 7 : (id >= 84) ? 6 : (id >= 60) ? 5 : (id >= 40) ? 4
                : (id >= 24) ? 3 : (id >= 12) ? 2 : (id >= 4) ? 1 : 0;
    const int nc = g + 1;
    const int local = id - 2 * g * nc;
    const int qi = local / nc;
    const int c = local - qi * nc;
    const int qt = 4 * g + qi;
    const int q0 = qt * 64;
    const int start = 4 * c;
    const int end = min(start + 4, qt + 1);

    const int w = tid >> 6, lane = tid & 63;
    const int quad = lane >> 4, l16 = lane & 15;

    // Q B-frag direct from global: lane l16 -> qrow, k = quad*8+j
    const int qrow = q0 + w * 16 + l16;
    const bf16* Qrow = &Q[((size_t)b * 2048 + qrow) * 128];
    short8 qf[4];
#pragma unroll
    for (int k4 = 0; k4 < 4; k4++)
        qf[k4] = *(const short8*)&Qrow[k4 * 32 + quad * 8];

    float m_run = -1.0e30f, l_run = 0.f;  // per-lane q-row stats (log2 domain)
    floatx4 o[8];                         // O^T: col qrow=l16, rows d
#pragma unroll
    for (int d = 0; d < 8; d++) o[d] = (floatx4){0.f, 0.f, 0.f, 0.f};

    int4 kreg[4], vreg[4];
    const int sr[4]  = {(tid + 0) >> 4, (tid + 256) >> 4, (tid + 512) >> 4, (tid + 768) >> 4};
    const int scg    = (tid & 15) * 8;
    const int sr2[4] = {(tid + 0) >> 3, (tid + 256) >> 3, (tid + 512) >> 3, (tid + 768) >> 3};
    const int scg2   = (tid & 7) * 8;

#pragma unroll
    for (int i = 0; i < 4; i++) {
        kreg[i] = *(const int4*)&K[((size_t)b * 2048 + start * 64 + sr[i]) * 128 + scg];
        vreg[i] = *(const int4*)&Vt[(size_t)b * 262144 + (size_t)sr2[i] * 2048 + start * 64 + scg2];
    }

    for (int kt = start; kt < end; kt++) {
        __syncthreads();
#pragma unroll
        for (int i = 0; i < 4; i++) {
            *(int4*)&Ks[sr[i] * 136 + scg] = kreg[i];
            *(int4*)&Vs[sr2[i] * 72 + scg2] = vreg[i];
        }
        __syncthreads();

        if (kt + 1 < end) {
#pragma unroll
            for (int i = 0; i < 4; i++) {
                kreg[i] = *(const int4*)&K[((size_t)b * 2048 + (kt + 1) * 64 + sr[i]) * 128 + scg];
                vreg[i] = *(const int4*)&Vt[(size_t)b * 262144 + (size_t)sr2[i] * 2048 + (kt + 1) * 64 + scg2];
            }
        }

        // S^T = K * Q^T : A = K rows (kcols), B = qf. D col = qrow (l16)
        floatx4 s_acc[4];
#pragma unroll
        for (int nt = 0; nt < 4; nt++) {
            s_acc[nt] = (floatx4){0.f, 0.f, 0.f, 0.f};
#pragma unroll
            for (int k4 = 0; k4 < 4; k4++) {
                short8 kf = *(const short8*)&Ks[(nt * 16 + l16) * 136 + k4 * 32 + quad * 8];
                s_acc[nt] = __builtin_amdgcn_mfma_f32_16x16x32_bf16(kf, qf[k4], s_acc[nt], 0, 0, 0);
            }
        }

        // per-lane 16 scores for q-row qrow, kcols kt*64 + nt*16 + quad*4 + r
        float sv[4][4];
#pragma unroll
        for (int nt = 0; nt < 4; nt++)
#pragma unroll
            for (int r = 0; r < 4; r++) {
                float s = s_acc[nt][r] * SCALE_L2;  // log2 domain
                if (kt == qt) {
                    int kcol = kt * 64 + nt * 16 + quad * 4 + r;
                    if (kcol > qrow) s = -1.0e9f;
                }
                sv[nt][r] = s;
            }

        float t0 = fmaxf(fmaxf(sv[0][0], sv[0][1]), fmaxf(sv[0][2], sv[0][3]));
        float t1 = fmaxf(fmaxf(sv[1][0], sv[1][1]), fmaxf(sv[1][2], sv[1][3]));
        float t2 = fmaxf(fmaxf(sv[2][0], sv[2][1]), fmaxf(sv[2][2], sv[2][3]));
        float t3 = fmaxf(fmaxf(sv[3][0], sv[3][1]), fmaxf(sv[3][2], sv[3][3]));
        float tmax = fmaxf(fmaxf(t0, t1), fmaxf(t2, t3));
        tmax = fmaxf(tmax, __shfl_xor(tmax, 16));
        tmax = fmaxf(tmax, __shfl_xor(tmax, 32));

        float mnew = fmaxf(m_run, tmax);
        float alpha = exp2f(m_run - mnew);
        m_run = mnew;

        float rsum = 0.f;
#pragma unroll
        for (int nt = 0; nt < 4; nt++)
#pragma unroll
            for (int r = 0; r < 4; r++) {
                float p = exp2f(sv[nt][r] - mnew);
                sv[nt][r] = p;
                rsum += p;
            }
        rsum += __shfl_xor(rsum, 16);
        rsum += __shfl_xor(rsum, 32);
        l_run = l_run * alpha + rsum;

        // P strip (per-wave, same-wave RAW): Ps[w][l16=qrow][kcol 0..63]
#pragma unroll
        for (int nt = 0; nt < 4; nt++) {
            ushort4 pk;
            pk.x = f2b(sv[nt][0]); pk.y = f2b(sv[nt][1]);
            pk.z = f2b(sv[nt][2]); pk.w = f2b(sv[nt][3]);
            *(ushort4*)&Ps[w * 1152 + l16 * 72 + nt * 16 + quad * 4] = pk;
        }

#pragma unroll
        for (int d = 0; d < 8; d++) {
            o[d][0] *= alpha; o[d][1] *= alpha; o[d][2] *= alpha; o[d][3] *= alpha;
        }

        // O^T += V^T * P^T : A = Vs rows (d), B = P strip rows (qrow=l16)
        short8 pf[2];
#pragma unroll
        for (int k2 = 0; k2 < 2; k2++)
            pf[k2] = *(const short8*)&Ps[w * 1152 + l16 * 72 + k2 * 32 + quad * 8];
#pragma unroll
        for (int d = 0; d < 8; d++)
#pragma unroll
            for (int k2 = 0; k2 < 2; k2++) {
                short8 vf = *(const short8*)&Vs[(d * 16 + l16) * 72 + k2 * 32 + quad * 8];
                o[d] = __builtin_amdgcn_mfma_f32_16x16x32_bf16(vf, pf[k2], o[d], 0, 0, 0);
            }
    }

    // epilogue: unnormalized O^T partials (bf16) -> Opb[x][lrow][d]
    const int lrow = w * 16 + l16;
    const size_t obase = ((size_t)x * 64 + lrow) * 128;
#pragma unroll
    for (int d = 0; d < 8; d++) {
        ushort4 pk;
        pk.x = f2b(o[d][0]); pk.y = f2b(o[d][1]);
        pk.z = f2b(o[d][2]); pk.w = f2b(o[d][3]);
        *(ushort4*)&Opb[obase + d * 16 + quad * 4] = pk;
    }
    if (lane < 16) Ml[(size_t)x * 64 + lrow] = make_float2(m_run, l_run);
}

// ---------------------------------------------------------------------------
// Merge variable-count chunk partials -> normalized bf16 scores Sc[8192][128]
// Row (b,qt) has nc = (qt>>2)+1 partials at chunk ids id0..id0+nc-1.
// ---------------------------------------------------------------------------
__global__ __launch_bounds__(256) void flash_merge(const bf16* __restrict__ Opb,
                                                   const float2* __restrict__ Ml,
                                                   bf16* __restrict__ Sc) {
    int idx = blockIdx.x * 256 + threadIdx.x;  // 8192*32
    int row = idx >> 5, dg = (idx & 31) * 4;
    int b = row >> 11, s = row & 2047;
    int qt = s >> 6, rl = s & 63;
    int g = qt >> 2, nc = g + 1;
    int id0 = b * 144 + 2 * g * nc + (qt & 3) * nc;

    float m[8], l[8], M = -1.0e30f;
    for (int j = 0; j < nc; j++) {
        float2 t = Ml[(size_t)(id0 + j) * 64 + rl];
        m[j] = t.x; l[j] = t.y;
        M = fmaxf(M, t.x);
    }
    float L = 0.f;
    float a0 = 0.f, a1 = 0.f, a2 = 0.f, a3 = 0.f;
    for (int j = 0; j < nc; j++) {
        float wj = exp2f(m[j] - M);
        L += l[j] * wj;
        ushort4 p = *(const ushort4*)&Opb[((size_t)(id0 + j) * 64 + rl) * 128 + dg];
        a0 += wj * b2f(p.x); a1 += wj * b2f(p.y);
        a2 += wj * b2f(p.z); a3 += wj * b2f(p.w);
    }
    float inv = 1.0f / L;
    ushort4 o;
    o.x = f2b(a0 * inv); o.y = f2b(a1 * inv);
    o.z = f2b(a2 * inv); o.w = f2b(a3 * inv);
    *(ushort4*)&Sc[(size_t)row * 128 + dg] = o;
}

// ---------------------------------------------------------------------------
extern "C" void kernel_launch(void* const* d_in, const int* in_sizes, int n_in,
                              void* d_out, int out_size, void* d_ws, size_t ws_size,
                              hipStream_t stream) {
    const float* enc = (const float*)d_in[0];
    // d_in[1] = mask: known causal triu(k=1); implemented analytically.
    const float* Wq = (const float*)d_in[2];
    const float* Wk = (const float*)d_in[3];
    const float* Wv = (const float*)d_in[4];
    const float* Wo = (const float*)d_in[5];
    float* out = (float*)d_out;

    const size_t MB = 1024 * 1024;
    char* ws = (char*)d_ws;
    bf16*   encb  = (bf16*)(ws);                    // 16 MB (dead after gemm_qkv)
    bf16*   Opb   = (bf16*)(ws);                    // 9.25 MB partials, alias encb
    bf16*   Qb    = (bf16*)(ws + 16 * MB);          // 2 MB
    bf16*   Kb    = (bf16*)(ws + 18 * MB);          // 2 MB
    bf16*   Vtb   = (bf16*)(ws + 20 * MB);          // 2 MB  [B][128][2048]
    bf16*   Scb   = (bf16*)(ws + 22 * MB);          // 2 MB
    bf16*   Wqkvt = (bf16*)(ws + 24 * MB);          // 768 KB [384][1024]
    bf16*   Wot   = (bf16*)(ws + 24 * MB + 768 * 1024);   // 256 KB [1024][128]
    float2* Ml    = (float2*)(ws + 25 * MB);        // 288 KB [576][64]

    prep_all<<<10240, 256, 0, stream>>>((const float4*)enc, (ushort4*)encb,
                                        Wq, Wk, Wv, Wo, Wqkvt, Wot);

    dim3 blk(256);
    gemm_qkv<<<dim3(128, 3), blk, 0, stream>>>(encb, Wqkvt, Qb, Kb, Vtb);

    flash_split<<<576, blk, 0, stream>>>(Qb, Kb, Vtb, Opb, Ml);
    flash_merge<<<1024, blk, 0, stream>>>(Opb, Ml, Scb);

    gemm_out<<<dim3(128, 8), blk, 0, stream>>>(Scb, Wot, out);
}